// Round 5
// baseline (3131.099 us; speedup 1.0000x reference)
//
#include <hip/hip_runtime.h>

// RNN scan on MI355X — round 5: column-split x2 (8 CUs).
// k1: xw[t][b][n] = bf16(x[b,t,:] @ W_x + b_x + b_h)   (unchanged)
// k2: grid=8: rowgroup = blk>>1 (16 batch rows), member = blk&1 (256 cols).
//     Whole W_h column-slice in VGPR A-frags wfA[2][16] (128 VGPRs),
//     indexed by LOCAL slot (0-7 own-half k, 8-15 partner-half k) so all
//     register indices are compile-time (round-2 spill fix). h exchanged via
//     agent-scope relaxed b64 atomics (frag-linear 8 KB blocks, double
//     buffered); own half also in LDS (double buffered) -> ONE barrier/step.
//     All threads poll the partner's monotonic flag. FC epilogue fused
//     (per-member partial + atomicAdd into zeroed d_out).

#define T_STEPS 1024
#define HID     512

typedef __attribute__((ext_vector_type(8))) short  short8;   // 8 bf16 (MFMA A/B frag)
typedef __attribute__((ext_vector_type(4))) short  short4_t; // 4 bf16 (8 B)
typedef __attribute__((ext_vector_type(4))) float  f32x4;    // MFMA C/D frag

typedef unsigned short     ushort_t;
typedef unsigned int       uint_t;
typedef unsigned long long ull_t;

__device__ __forceinline__ ushort_t f2bf(float f) {
    union { float f; uint_t u; } c; c.f = f;
    uint_t u = c.u;
    return (ushort_t)((u + 0x7fffu + ((u >> 16) & 1u)) >> 16);   // RNE
}
__device__ __forceinline__ float bf2f(ushort_t h) {
    union { uint_t u; float f; } c; c.u = ((uint_t)h) << 16;
    return c.f;
}
// tanh(x) = 1 - 2/(e^{2x}+1); exp2-based, saturates correctly at +/-1.
__device__ __forceinline__ float tanh_fast(float x) {
    float t = __builtin_amdgcn_exp2f(x * 2.88539008f);   // e^{2x}
    return 1.0f - 2.0f * __builtin_amdgcn_rcpf(t + 1.0f);
}

// ---------------------------------------------------------------------------
// k1: xw[t][b][n] = x @ W_x + (b_x + b_h), transposed MFMA: A = W_x^T (m=n),
// B = x^T (n=b). 64n x 64b tile per WG, BK=32. (unchanged from round 4)
// ---------------------------------------------------------------------------
__global__ __launch_bounds__(256) void k1_xproj(
    const float* __restrict__ x, const float* __restrict__ Wx,
    const float* __restrict__ bx, const float* __restrict__ bh,
    ushort_t* __restrict__ xw)
{
    __shared__ __align__(16) ushort_t Wl[64 * 40];   // [n][k] bf16 (A-side)
    __shared__ __align__(16) ushort_t Xl[64 * 40];   // [b][k] bf16 (B-side)

    const int t0   = blockIdx.y;
    const int n0   = blockIdx.x * 64;
    const int tid  = threadIdx.x;
    const int wave = tid >> 6;
    const int lane = tid & 63;
    const int lm   = lane & 15;
    const int quad = lane >> 4;

    f32x4 acc[4];
    #pragma unroll
    for (int i = 0; i < 4; ++i) acc[i] = (f32x4){0.f, 0.f, 0.f, 0.f};

    float biasv[4];
    #pragma unroll
    for (int r = 0; r < 4; ++r) {
        int n = n0 + wave * 16 + quad * 4 + r;
        biasv[r] = bx[n] + bh[n];
    }

    const int ar = tid >> 2, ac = (tid & 3) * 8;
    const int bk = tid >> 3, bc = (tid & 7) * 8;

    for (int kb = 0; kb < 16; ++kb) {
        {
            const float* ap = x + ((size_t)ar * T_STEPS + t0) * HID + kb * 32 + ac;
            short8 pack;
            #pragma unroll
            for (int i = 0; i < 8; ++i) pack[i] = (short)f2bf(ap[i]);
            *(short8*)&Xl[ar * 40 + ac] = pack;
        }
        {
            const float* bp = Wx + (size_t)(kb * 32 + bk) * HID + n0 + bc;
            #pragma unroll
            for (int i = 0; i < 8; ++i) Wl[(bc + i) * 40 + bk] = f2bf(bp[i]);
        }
        __syncthreads();
        short8 afr = *(const short8*)&Wl[(wave * 16 + lm) * 40 + quad * 8];
        #pragma unroll
        for (int bt = 0; bt < 4; ++bt) {
            short8 bfr = *(const short8*)&Xl[(bt * 16 + lm) * 40 + quad * 8];
            acc[bt] = __builtin_amdgcn_mfma_f32_16x16x32_bf16(afr, bfr, acc[bt], 0, 0, 0);
        }
        __syncthreads();
    }

    #pragma unroll
    for (int bt = 0; bt < 4; ++bt) {
        short4_t pk;
        #pragma unroll
        for (int r = 0; r < 4; ++r) pk[r] = (short)f2bf(acc[bt][r] + biasv[r]);
        *(short4_t*)&xw[((size_t)t0 * 64 + bt * 16 + lm) * HID
                        + n0 + wave * 16 + quad * 4] = pk;
    }
}

// ---------------------------------------------------------------------------
// k2. Frag-linear h block (per (slot,rg,member), 4096 ush = 8 KB):
//   element (b, klocal) at (kt*64 + ((klocal>>3)&3)*16 + b)*8 + (klocal&7),
//   kt = klocal>>5. Wave w writes exactly kt = w of its member block.
// ---------------------------------------------------------------------------
__global__ __launch_bounds__(512, 2) void k2_scan(
    const ushort_t* __restrict__ xw, const float* __restrict__ Wh,
    const float* __restrict__ Wfc, const float* __restrict__ bfc,
    float* __restrict__ out, ushort_t* __restrict__ hg,
    uint_t* __restrict__ flags)
{
    __shared__ __align__(16) ushort_t hT[2][4096];   // own half, double-buffered

    const int tid  = threadIdx.x;
    const int wave = tid >> 6;
    const int lane = tid & 63;
    const int lm   = lane & 15;
    const int quad = lane >> 4;
    const int rg      = blockIdx.x >> 1;
    const int member  = blockIdx.x & 1;
    const int rowbase = rg * 16;
    const int nbase   = member * 256 + wave * 32;    // wave's first output col

    for (int i = tid; i < 8192; i += 512) ((ushort_t*)hT)[i] = 0;   // h_0 = 0

    // wfA[mt][p]: A[m = nbase+mt*16+lm][k]. p 0-7: own-half kt (member*8+p),
    // p 8-15: partner-half kt ((1-member)*8+p-8). member only in ADDRESSES.
    short8 wfA[2][16];
    #pragma unroll
    for (int mt = 0; mt < 2; ++mt) {
        const int n = nbase + mt * 16 + lm;
        #pragma unroll
        for (int p = 0; p < 16; ++p) {
            const int kt_g = (p < 8) ? (member * 8 + p) : ((1 - member) * 8 + (p - 8));
            short8 w;
            #pragma unroll
            for (int j = 0; j < 8; ++j)
                w[j] = (short)f2bf(Wh[(size_t)(kt_g * 32 + quad * 8 + j) * HID + n]);
            wfA[mt][p] = w;
        }
    }
    __syncthreads();

    uint_t* pflag = flags + (rg * 2 + (1 - member)) * 16;
    uint_t* mflag = flags + (rg * 2 + member) * 16;

    for (int t = 0; t < T_STEPS; ++t) {
        if (t) {
            while (__hip_atomic_load(pflag, __ATOMIC_RELAXED, __HIP_MEMORY_SCOPE_AGENT)
                   < (uint_t)t)
                __builtin_amdgcn_s_sleep(1);
        }

        // partner half: 8 kt x 16B per lane, agent-scope b64 loads
        const ushort_t* pblk = hg + (size_t)(((t & 1) * 8) + rg * 2 + (1 - member)) * 4096;
        ull_t pl[8][2];
        #pragma unroll
        for (int kk = 0; kk < 8; ++kk) {
            const ull_t* p = (const ull_t*)(pblk + (kk * 64 + lane) * 8);
            pl[kk][0] = __hip_atomic_load(p,     __ATOMIC_RELAXED, __HIP_MEMORY_SCOPE_AGENT);
            pl[kk][1] = __hip_atomic_load(p + 1, __ATOMIC_RELAXED, __HIP_MEMORY_SCOPE_AGENT);
        }

        // xw for this step (needed only pre-tanh)
        short4_t xv[2];
        #pragma unroll
        for (int mt = 0; mt < 2; ++mt)
            xv[mt] = *(const short4_t*)&xw[((size_t)t * 64 + rowbase + lm) * HID
                                           + nbase + mt * 16 + quad * 4];

        f32x4 acc[2];
        acc[0] = (f32x4){0.f, 0.f, 0.f, 0.f};
        acc[1] = (f32x4){0.f, 0.f, 0.f, 0.f};

        // own-half k from LDS (runs while partner loads are in flight)
        const ushort_t* cur = hT[t & 1];
        #pragma unroll
        for (int kk = 0; kk < 8; ++kk) {
            short8 b = *(const short8*)&cur[(kk * 64 + lane) * 8];
            acc[0] = __builtin_amdgcn_mfma_f32_16x16x32_bf16(wfA[0][kk], b, acc[0], 0, 0, 0);
            acc[1] = __builtin_amdgcn_mfma_f32_16x16x32_bf16(wfA[1][kk], b, acc[1], 0, 0, 0);
        }
        // partner-half k from the exchanged registers
        #pragma unroll
        for (int kk = 0; kk < 8; ++kk) {
            union { ull_t u[2]; short8 v; } pk;
            pk.u[0] = pl[kk][0]; pk.u[1] = pl[kk][1];
            acc[0] = __builtin_amdgcn_mfma_f32_16x16x32_bf16(wfA[0][8 + kk], pk.v, acc[0], 0, 0, 0);
            acc[1] = __builtin_amdgcn_mfma_f32_16x16x32_bf16(wfA[1][8 + kk], pk.v, acc[1], 0, 0, 0);
        }

        // tanh -> LDS (next slot) + global own block (next slot)
        ushort_t* nxt  = hT[(t + 1) & 1];
        ushort_t* gdst = hg + (size_t)((((t + 1) & 1) * 8) + rg * 2 + member) * 4096;
        #pragma unroll
        for (int mt = 0; mt < 2; ++mt) {
            short4_t pk4;
            #pragma unroll
            for (int r = 0; r < 4; ++r)
                pk4[r] = (short)f2bf(tanh_fast(acc[mt][r] + bf2f((ushort_t)xv[mt][r])));
            const int off = (wave * 64 + (mt * 2 + (quad >> 1)) * 16 + lm) * 8
                            + (quad & 1) * 4;
            *(short4_t*)&nxt[off] = pk4;
            union { short4_t v; ull_t u; } cv; cv.v = pk4;
            __hip_atomic_store((ull_t*)(gdst + off), cv.u,
                               __ATOMIC_RELAXED, __HIP_MEMORY_SCOPE_AGENT);
        }

        __syncthreads();   // vmcnt(0)+lgkmcnt(0) drain: release for the flag
        if (tid == 0)
            __hip_atomic_store(mflag, (uint_t)(t + 1),
                               __ATOMIC_RELAXED, __HIP_MEMORY_SCOPE_AGENT);
    }

    // fused FC: partial over this member's 256 k, atomicAdd into zeroed out.
    const ushort_t* fin = hT[T_STEPS & 1];
    #pragma unroll
    for (int bb = 0; bb < 2; ++bb) {
        const int b = wave * 2 + bb;
        // lane covers klocal = lane*4 .. +4 (one b64)
        const short4_t hv = *(const short4_t*)&fin[((lane >> 3) * 64
                              + ((lane >> 1) & 3) * 16 + b) * 8 + (lane & 1) * 4];
        float s = 0.f;
        #pragma unroll
        for (int j = 0; j < 4; ++j)
            s += bf2f((ushort_t)hv[j]) * Wfc[member * 256 + lane * 4 + j];
        #pragma unroll
        for (int off = 32; off; off >>= 1) s += __shfl_down(s, off, 64);
        if (lane == 0)
            atomicAdd(&out[rowbase + b], s + (member == 0 ? bfc[0] : 0.f));
    }
}

// ---------------------------------------------------------------------------
extern "C" void kernel_launch(void* const* d_in, const int* in_sizes, int n_in,
                              void* d_out, int out_size, void* d_ws, size_t ws_size,
                              hipStream_t stream)
{
    const float* x   = (const float*)d_in[0];
    const float* Wx  = (const float*)d_in[1];
    const float* bx  = (const float*)d_in[2];
    const float* Wh  = (const float*)d_in[3];
    const float* bh  = (const float*)d_in[4];
    const float* Wfc = (const float*)d_in[5];
    const float* bfc = (const float*)d_in[6];
    float* out = (float*)d_out;

    char* ws = (char*)d_ws;
    // ws layout:
    //   [0, 67108864)            xw bf16 [1024 t][64 b][512 n]
    //   [67108864, +131072)      hg: [2 slot][4 rg][2 member][4096 ush]
    //   [67239936, +512)         flags (8 x 64B-spaced u32)
    ushort_t* xw    = (ushort_t*)ws;
    ushort_t* hg    = (ushort_t*)(ws + 67108864);
    uint_t*   flags = (uint_t*)(ws + 67108864 + 131072);

    hipMemsetAsync(ws + 67108864, 0, 131072 + 512, stream);   // h_0 = 0, flags = 0
    hipMemsetAsync(d_out, 0, 64 * sizeof(float), stream);     // FC accum target

    k1_xproj<<<dim3(8, 1024), 256, 0, stream>>>(x, Wx, bx, bh, xw);
    k2_scan <<<dim3(8),       512, 0, stream>>>(xw, Wh, Wfc, bfc, out, hg, flags);
}